// Round 10
// baseline (1847.983 us; speedup 1.0000x reference)
//
#include <hip/hip_runtime.h>

#define H    64
#define TT   1024
#define NW   512    // 8 waves: 0-3 = A (layer0), 4-7 = B (layer1: gx+gh)
#define NWG  256
#define XSTR 1032   // xs row stride (floats)
#define HRUS 136    // h row stride in ushorts (272 B = 68 dw; 68 % 32 == 4 -> <=2-way)

typedef float  f32x4  __attribute__((ext_vector_type(4)));
typedef __bf16 bf16x8 __attribute__((ext_vector_type(8)));

__device__ __forceinline__ unsigned short bf16_rne(float f) {
    unsigned u = __float_as_uint(f);
    u += 0x7FFFu + ((u >> 16) & 1u);
    return (unsigned short)(u >> 16);
}
__device__ __forceinline__ float fast_sigmoid(float x) {
    return __builtin_amdgcn_rcpf(1.0f + __expf(-x));
}
__device__ __forceinline__ float fast_tanh(float x) {
    float xx = fminf(fmaxf(x, -15.0f), 15.0f);
    float e  = __expf(2.0f * xx);
    return (e - 1.0f) * __builtin_amdgcn_rcpf(e + 1.0f);
}

// Antiphase 2-stage pipeline. Barrier clock has EVEN and ODD phases per s:
//   EVEN: A: read h0(s-1) frags (hB0[(s+1)&1]) + 18 MFMA -> dA   [s<TT]
//         B: gate h1(s-2) from dB, write hB1                      [s>=2]
//   ODD:  A: gate h0(s) from dA + x(s), write hB0[s&1]            [s<TT]
//         B: read h0(s-1) + h1(s-2) frags, 36 MFMA -> dB          [1<=s<=TT]
// MFMA issue/drain of one group overlaps gate VALU of the other every interval.
// h1 is single-buffered (write EVEN, read ODD); h0 double-buffered.
// dA/dB live across one barrier in registers. gx stays in B's registers.
// Split-bf16 numerics identical to R4: w*h ~= whi*hhi + whi*hlo + wlo*hhi.
__global__ __launch_bounds__(NW, 2) void gru_anti8(
    const float* __restrict__ x,
    const float* __restrict__ w_ih0, const float* __restrict__ w_hh0,
    const float* __restrict__ b_ih0, const float* __restrict__ b_hh0,
    const float* __restrict__ w_ih1, const float* __restrict__ w_hh1,
    const float* __restrict__ b_ih1, const float* __restrict__ b_hh1,
    const float* __restrict__ w_fc,  const float* __restrict__ b_fc,
    float* __restrict__ out)
{
    __shared__ __align__(16) float          xs[8 * XSTR];        // 33 KB
    __shared__ __align__(16) unsigned short hB0[2][8 * HRUS];    // 4.3 KB
    __shared__ __align__(16) unsigned short hB1[8 * HRUS];       // 2.2 KB

    const int tid  = threadIdx.x;
    const int wave = tid >> 6;
    const int lane = tid & 63;
    const int r    = lane & 15;
    const int q    = lane >> 4;
    const int b    = r & 7;
    const int b0g  = blockIdx.x * 8;
    const bool gB  = (wave >= 4);
    const int  w4  = wave & 3;
    const int  jb  = 16 * w4 + 4 * q;    // owned gate cols jb..jb+3

    for (int i = tid; i < 2 * 8 * HRUS; i += NW) (&hB0[0][0])[i] = 0;
    for (int i = tid; i < 8 * HRUS;     i += NW) hB1[i] = 0;

    {   // stage x: wave w copies batch row b0g+w
        const float* xrow = x + (size_t)(b0g + wave) * TT;
        float* xd = xs + wave * XSTR;
        #pragma unroll
        for (int u = 0; u < 4; ++u) {
            int idx = (u * 64 + lane) * 4;
            *(float4*)(xd + idx) = *(const float4*)(xrow + idx);
        }
    }

    // ---- weight fragments: 6 slots (A uses 0-2; B: 0-2 = Wih1, 3-5 = Whh1) ----
    bf16x8 whi[6][2], wlo[6][2];
    #pragma unroll
    for (int i = 0; i < 6; ++i) {
        const float* W = gB ? ((i < 3) ? w_ih1 : w_hh1) : w_hh0;
        const int row0 = 64 * (i % 3) + 16 * w4;
        #pragma unroll
        for (int c = 0; c < 2; ++c) {
            const float* wp = W + (row0 + r) * H + 32 * c + 8 * q;
            float4 p0 = *(const float4*)wp;
            float4 p1 = *(const float4*)(wp + 4);
            float f[8] = {p0.x,p0.y,p0.z,p0.w,p1.x,p1.y,p1.z,p1.w};
            unsigned short uh[8], ul[8];
            #pragma unroll
            for (int j = 0; j < 8; ++j) {
                unsigned short h16 = bf16_rne(f[j]);
                uh[j] = h16;
                ul[j] = bf16_rne(f[j] - __uint_as_float((unsigned)h16 << 16));
            }
            whi[i][c] = *(const bf16x8*)uh;
            wlo[i][c] = *(const bf16x8*)ul;
        }
    }

    // ---- gate constants for the 4 owned units ----
    float gwr[4], gwz[4], gwn[4], gcr[4], gcz[4], gbn[4], ghn[4];
    #pragma unroll
    for (int k = 0; k < 4; ++k) {
        const int j = jb + k;
        if (gB) {
            gwr[k] = gwz[k] = gwn[k] = 0.0f;
            gcr[k] = b_ih1[j]      + b_hh1[j];
            gcz[k] = b_ih1[64+j]   + b_hh1[64+j];
            gbn[k] = b_ih1[128+j];
            ghn[k] = b_hh1[128+j];
        } else {
            gwr[k] = w_ih0[j]; gwz[k] = w_ih0[64+j]; gwn[k] = w_ih0[128+j];
            gcr[k] = b_ih0[j]      + b_hh0[j];
            gcz[k] = b_ih0[64+j]   + b_hh0[64+j];
            gbn[k] = b_ih0[128+j];
            ghn[k] = b_hh0[128+j];
        }
    }
    const float wfc = w_fc[lane];

#define TILE6(dacc, i, u0, u1, v0, v1) \
    dacc = __builtin_amdgcn_mfma_f32_16x16x32_bf16(whi[i][0], u0, dacc, 0,0,0); \
    dacc = __builtin_amdgcn_mfma_f32_16x16x32_bf16(whi[i][1], u1, dacc, 0,0,0); \
    dacc = __builtin_amdgcn_mfma_f32_16x16x32_bf16(whi[i][0], v0, dacc, 0,0,0); \
    dacc = __builtin_amdgcn_mfma_f32_16x16x32_bf16(whi[i][1], v1, dacc, 0,0,0); \
    dacc = __builtin_amdgcn_mfma_f32_16x16x32_bf16(wlo[i][0], u0, dacc, 0,0,0); \
    dacc = __builtin_amdgcn_mfma_f32_16x16x32_bf16(wlo[i][1], u1, dacc, 0,0,0);

    float hst[4] = {0.0f, 0.0f, 0.0f, 0.0f};
    float dxv = 0.0f;
    f32x4 dA0={0,0,0,0}, dA1={0,0,0,0}, dA2={0,0,0,0};
    f32x4 dB0={0,0,0,0}, dB1={0,0,0,0}, dB2={0,0,0,0};
    f32x4 dB3={0,0,0,0}, dB4={0,0,0,0}, dB5={0,0,0,0};

    __syncthreads();

    #pragma unroll 1
    for (int s = 0; s <= TT + 1; ++s) {
        // ================= EVEN phase =================
        if (!gB) {
            if (s < TT) {
                const unsigned short* f0 = &hB0[(s + 1) & 1][b * HRUS];
                const bf16x8 u0 = *(const bf16x8*)(f0 + 8 * q);
                const bf16x8 u1 = *(const bf16x8*)(f0 + 32 + 8 * q);
                const bf16x8 v0 = *(const bf16x8*)(f0 + 64 + 8 * q);
                const bf16x8 v1 = *(const bf16x8*)(f0 + 96 + 8 * q);
                dxv = xs[b * XSTR + s];
                f32x4 a0={0,0,0,0}, a1={0,0,0,0}, a2={0,0,0,0};
                __builtin_amdgcn_s_setprio(1);
                TILE6(a0, 0, u0, u1, v0, v1)
                TILE6(a1, 1, u0, u1, v0, v1)
                TILE6(a2, 2, u0, u1, v0, v1)
                __builtin_amdgcn_s_setprio(0);
                dA0 = a0; dA1 = a1; dA2 = a2;
            }
        } else {
            if (s >= 2) {   // gate h1(s-2)
                #pragma unroll
                for (int k = 0; k < 4; ++k) {
                    float rr = fast_sigmoid(dB0[k] + dB3[k] + gcr[k]);
                    float zz = fast_sigmoid(dB1[k] + dB4[k] + gcz[k]);
                    float nn = fast_tanh(dB2[k] + gbn[k] + rr * (dB5[k] + ghn[k]));
                    hst[k] = fmaf(zz, hst[k] - nn, nn);
                }
                if (r < 8) {
                    ushort4 hv, lv;
                    unsigned short h0_ = bf16_rne(hst[0]);
                    unsigned short h1_ = bf16_rne(hst[1]);
                    unsigned short h2_ = bf16_rne(hst[2]);
                    unsigned short h3_ = bf16_rne(hst[3]);
                    hv.x=h0_; hv.y=h1_; hv.z=h2_; hv.w=h3_;
                    lv.x = bf16_rne(hst[0] - __uint_as_float((unsigned)h0_ << 16));
                    lv.y = bf16_rne(hst[1] - __uint_as_float((unsigned)h1_ << 16));
                    lv.z = bf16_rne(hst[2] - __uint_as_float((unsigned)h2_ << 16));
                    lv.w = bf16_rne(hst[3] - __uint_as_float((unsigned)h3_ << 16));
                    unsigned short* wdst = hB1 + b * HRUS + jb;
                    *(ushort4*)(wdst)      = hv;
                    *(ushort4*)(wdst + 64) = lv;
                }
            }
        }
        __syncthreads();

        // ================= ODD phase =================
        if (!gB) {
            if (s < TT) {   // gate h0(s)
                #pragma unroll
                for (int k = 0; k < 4; ++k) {
                    float rr = fast_sigmoid(fmaf(dxv, gwr[k], gcr[k]) + dA0[k]);
                    float zz = fast_sigmoid(fmaf(dxv, gwz[k], gcz[k]) + dA1[k]);
                    float nn = fast_tanh(fmaf(dxv, gwn[k], gbn[k]) + rr * (dA2[k] + ghn[k]));
                    hst[k] = fmaf(zz, hst[k] - nn, nn);
                }
                if (r < 8) {
                    ushort4 hv, lv;
                    unsigned short h0_ = bf16_rne(hst[0]);
                    unsigned short h1_ = bf16_rne(hst[1]);
                    unsigned short h2_ = bf16_rne(hst[2]);
                    unsigned short h3_ = bf16_rne(hst[3]);
                    hv.x=h0_; hv.y=h1_; hv.z=h2_; hv.w=h3_;
                    lv.x = bf16_rne(hst[0] - __uint_as_float((unsigned)h0_ << 16));
                    lv.y = bf16_rne(hst[1] - __uint_as_float((unsigned)h1_ << 16));
                    lv.z = bf16_rne(hst[2] - __uint_as_float((unsigned)h2_ << 16));
                    lv.w = bf16_rne(hst[3] - __uint_as_float((unsigned)h3_ << 16));
                    unsigned short* wdst = hB0[s & 1] + b * HRUS + jb;
                    *(ushort4*)(wdst)      = hv;
                    *(ushort4*)(wdst + 64) = lv;
                }
            }
        } else {
            if (s >= 1 && s <= TT) {
                // gx = Wih1 · h0(s-1)
                const unsigned short* f0 = &hB0[(s + 1) & 1][b * HRUS];
                {
                    const bf16x8 u0 = *(const bf16x8*)(f0 + 8 * q);
                    const bf16x8 u1 = *(const bf16x8*)(f0 + 32 + 8 * q);
                    const bf16x8 v0 = *(const bf16x8*)(f0 + 64 + 8 * q);
                    const bf16x8 v1 = *(const bf16x8*)(f0 + 96 + 8 * q);
                    f32x4 t0={0,0,0,0}, t1={0,0,0,0}, t2={0,0,0,0};
                    __builtin_amdgcn_s_setprio(1);
                    TILE6(t0, 0, u0, u1, v0, v1)
                    TILE6(t1, 1, u0, u1, v0, v1)
                    TILE6(t2, 2, u0, u1, v0, v1)
                    __builtin_amdgcn_s_setprio(0);
                    dB0 = t0; dB1 = t1; dB2 = t2;
                }
                // gh = Whh1 · h1(s-2)
                {
                    const unsigned short* f1 = hB1 + b * HRUS;
                    const bf16x8 u0 = *(const bf16x8*)(f1 + 8 * q);
                    const bf16x8 u1 = *(const bf16x8*)(f1 + 32 + 8 * q);
                    const bf16x8 v0 = *(const bf16x8*)(f1 + 64 + 8 * q);
                    const bf16x8 v1 = *(const bf16x8*)(f1 + 96 + 8 * q);
                    f32x4 t3={0,0,0,0}, t4={0,0,0,0}, t5={0,0,0,0};
                    __builtin_amdgcn_s_setprio(1);
                    TILE6(t3, 3, u0, u1, v0, v1)
                    TILE6(t4, 4, u0, u1, v0, v1)
                    TILE6(t5, 5, u0, u1, v0, v1)
                    __builtin_amdgcn_s_setprio(0);
                    dB3 = t3; dB4 = t4; dB5 = t5;
                }
            }
        }
        __syncthreads();
    }

    // ---- FC: h1(TT-1) is in hB1 rows 0-7 ----
    {
        const unsigned short* hrow = hB1 + wave * HRUS;
        float hi = __uint_as_float((unsigned)hrow[lane]      << 16);
        float lo = __uint_as_float((unsigned)hrow[64 + lane] << 16);
        float v = (hi + lo) * wfc;
        #pragma unroll
        for (int s = 32; s > 0; s >>= 1) v += __shfl_xor(v, s, 64);
        if (lane == 0) out[b0g + wave] = v + b_fc[0];
    }
}

extern "C" void kernel_launch(void* const* d_in, const int* in_sizes, int n_in,
                              void* d_out, int out_size, void* d_ws, size_t ws_size,
                              hipStream_t stream) {
    (void)in_sizes; (void)n_in; (void)out_size; (void)d_ws; (void)ws_size;
    gru_anti8<<<NWG, NW, 0, stream>>>(
        (const float*)d_in[0],
        (const float*)d_in[1], (const float*)d_in[2],
        (const float*)d_in[3], (const float*)d_in[4],
        (const float*)d_in[5], (const float*)d_in[6],
        (const float*)d_in[7], (const float*)d_in[8],
        (const float*)d_in[9], (const float*)d_in[10],
        (float*)d_out);
}

// Round 11
// 1133.176 us; speedup vs baseline: 1.6308x; 1.6308x over previous
//
#include <hip/hip_runtime.h>

#define H    64
#define TT   1024
#define NW   768    // 12 waves: 0-3 = A (Whh0), 4-7 = B1 (Wih1), 8-11 = B2 (Whh1)
#define NWG  256
#define XSTR 1032   // xs row stride (floats); 1032 % 32 == 8
#define HRUS 136    // h row stride in ushorts (272 B = 68 dw; 68 % 32 == 4)

typedef float  f32x4  __attribute__((ext_vector_type(4)));
typedef __bf16 bf16x8 __attribute__((ext_vector_type(8)));

__device__ __forceinline__ unsigned short bf16_rne(float f) {
    unsigned u = __float_as_uint(f);
    u += 0x7FFFu + ((u >> 16) & 1u);
    return (unsigned short)(u >> 16);
}
__device__ __forceinline__ float fast_sigmoid(float x) {
    return __builtin_amdgcn_rcpf(1.0f + __expf(-x));
}
__device__ __forceinline__ float fast_tanh(float x) {
    float xx = fminf(fmaxf(x, -15.0f), 15.0f);
    float e  = __expf(2.0f * xx);
    return (e - 1.0f) * __builtin_amdgcn_rcpf(e + 1.0f);
}

// Antiphase, 3 role groups, 3 tiles (12 frags) per wave, <=3 f32x4 cross-barrier:
//  P1(s): A : read h0(s-1) frags, 18 MFMA -> dA (crosses to P2)     [1<=s<=TT-1]
//         B1: read h0(s-1) frags, 18 MFMA, write gx(s-1) slot s&1   [1<=s<=TT]
//         B2: gate1(gx(s-2) slot (s&1)^1, dB) -> h1(s-2) -> hB1     [s>=2]
//  P2(s): A : gate0(dA, x(s)) -> h0(s) -> hB0[s&1]                  [s<=TT-1]
//         B2: read h1(s-2) frags, 18 MFMA -> dB (crosses to P1(s+1))[2<=s<=TT]
// Every phase overlaps one group's MFMA with another group's gate VALU.
// Recurrence check: h1(s-2) = gate(gx(s-2)=Wih1·h0(s-2), dB=Whh1·h1(s-3)). ✓
// Split-bf16 numerics identical to R9 (absmax 2.441e-4).
__global__ __launch_bounds__(NW, 2) void gru_anti9(
    const float* __restrict__ x,
    const float* __restrict__ w_ih0, const float* __restrict__ w_hh0,
    const float* __restrict__ b_ih0, const float* __restrict__ b_hh0,
    const float* __restrict__ w_ih1, const float* __restrict__ w_hh1,
    const float* __restrict__ b_ih1, const float* __restrict__ b_hh1,
    const float* __restrict__ w_fc,  const float* __restrict__ b_fc,
    float* __restrict__ out)
{
    __shared__ __align__(16) float          xs[8 * XSTR];        // 33 KB
    __shared__ __align__(16) unsigned short hB0[2][8 * HRUS];    // 4.3 KB
    __shared__ __align__(16) unsigned short hB1[8 * HRUS];       // 2.2 KB
    __shared__ __align__(16) float          gxb[2 * 1536];       // 12.3 KB [par][w4][type][q][b][k]

    const int tid  = threadIdx.x;
    const int wave = tid >> 6;
    const int lane = tid & 63;
    const int r    = lane & 15;
    const int q    = lane >> 4;
    const int b    = r & 7;
    const int b0g  = blockIdx.x * 8;
    const int g    = wave >> 2;          // 0=A, 1=B1, 2=B2
    const int w4   = wave & 3;
    const int jb   = 16 * w4 + 4 * q;    // owned gate cols jb..jb+3

    for (int i = tid; i < 2 * 8 * HRUS; i += NW) (&hB0[0][0])[i] = 0;
    for (int i = tid; i < 8 * HRUS;     i += NW) hB1[i] = 0;

    if (wave < 8) {   // stage x: wave w copies batch row b0g+w
        const float* xrow = x + (size_t)(b0g + wave) * TT;
        float* xd = xs + wave * XSTR;
        #pragma unroll
        for (int u = 0; u < 4; ++u) {
            int idx = (u * 64 + lane) * 4;
            *(float4*)(xd + idx) = *(const float4*)(xrow + idx);
        }
    }

    // ---- weight fragments: exactly 3 tiles (r,z,n rows) per wave ----
    const float* W = (g == 0) ? w_hh0 : (g == 1) ? w_ih1 : w_hh1;
    bf16x8 whi[3][2], wlo[3][2];
    #pragma unroll
    for (int i = 0; i < 3; ++i) {
        const int row0 = 64 * i + 16 * w4;
        #pragma unroll
        for (int c = 0; c < 2; ++c) {
            const float* wp = W + (row0 + r) * H + 32 * c + 8 * q;
            float4 p0 = *(const float4*)wp;
            float4 p1 = *(const float4*)(wp + 4);
            float f[8] = {p0.x,p0.y,p0.z,p0.w,p1.x,p1.y,p1.z,p1.w};
            unsigned short uh[8], ul[8];
            #pragma unroll
            for (int j = 0; j < 8; ++j) {
                unsigned short h16 = bf16_rne(f[j]);
                uh[j] = h16;
                ul[j] = bf16_rne(f[j] - __uint_as_float((unsigned)h16 << 16));
            }
            whi[i][c] = *(const bf16x8*)uh;
            wlo[i][c] = *(const bf16x8*)ul;
        }
    }

    // ---- gate constants for the 4 owned units (A: layer0, B2: layer1) ----
    float gwr[4], gwz[4], gwn[4], gcr[4], gcz[4], gbn[4], ghn[4];
    #pragma unroll
    for (int k = 0; k < 4; ++k) {
        const int j = jb + k;
        if (g == 0) {
            gwr[k] = w_ih0[j]; gwz[k] = w_ih0[64+j]; gwn[k] = w_ih0[128+j];
            gcr[k] = b_ih0[j]      + b_hh0[j];
            gcz[k] = b_ih0[64+j]   + b_hh0[64+j];
            gbn[k] = b_ih0[128+j];
            ghn[k] = b_hh0[128+j];
        } else if (g == 2) {
            gwr[k] = gwz[k] = gwn[k] = 0.0f;
            gcr[k] = b_ih1[j]      + b_hh1[j];
            gcz[k] = b_ih1[64+j]   + b_hh1[64+j];
            gbn[k] = b_ih1[128+j];
            ghn[k] = b_hh1[128+j];
        } else {
            gwr[k] = gwz[k] = gwn[k] = 0.0f;
            gcr[k] = gcz[k] = gbn[k] = ghn[k] = 0.0f;
        }
    }
    const float wfc = w_fc[lane];

    // gx flat layout: par*1536 + w4*384 + type*128 + q*32 + b*4 + k
    float* gxp = gxb + w4 * 384 + q * 32 + b * 4;

#define TILE6(dacc, i, u0, u1, v0, v1) \
    dacc = __builtin_amdgcn_mfma_f32_16x16x32_bf16(whi[i][0], u0, dacc, 0,0,0); \
    dacc = __builtin_amdgcn_mfma_f32_16x16x32_bf16(whi[i][1], u1, dacc, 0,0,0); \
    dacc = __builtin_amdgcn_mfma_f32_16x16x32_bf16(whi[i][0], v0, dacc, 0,0,0); \
    dacc = __builtin_amdgcn_mfma_f32_16x16x32_bf16(whi[i][1], v1, dacc, 0,0,0); \
    dacc = __builtin_amdgcn_mfma_f32_16x16x32_bf16(wlo[i][0], u0, dacc, 0,0,0); \
    dacc = __builtin_amdgcn_mfma_f32_16x16x32_bf16(wlo[i][1], u1, dacc, 0,0,0);

#define PACK_WRITE(dstp) { \
    ushort4 hv, lv; \
    unsigned short h0_ = bf16_rne(hst[0]); \
    unsigned short h1_ = bf16_rne(hst[1]); \
    unsigned short h2_ = bf16_rne(hst[2]); \
    unsigned short h3_ = bf16_rne(hst[3]); \
    hv.x=h0_; hv.y=h1_; hv.z=h2_; hv.w=h3_; \
    lv.x = bf16_rne(hst[0] - __uint_as_float((unsigned)h0_ << 16)); \
    lv.y = bf16_rne(hst[1] - __uint_as_float((unsigned)h1_ << 16)); \
    lv.z = bf16_rne(hst[2] - __uint_as_float((unsigned)h2_ << 16)); \
    lv.w = bf16_rne(hst[3] - __uint_as_float((unsigned)h3_ << 16)); \
    *(ushort4*)(dstp)      = hv; \
    *(ushort4*)((dstp)+64) = lv; }

    float hst[4] = {0.0f, 0.0f, 0.0f, 0.0f};
    float dxv = 0.0f;
    f32x4 dA0={0,0,0,0}, dA1={0,0,0,0}, dA2={0,0,0,0};   // A: P1 -> P2
    f32x4 dB0={0,0,0,0}, dB1={0,0,0,0}, dB2={0,0,0,0};   // B2: P2 -> P1(s+1)

    __syncthreads();

    #pragma unroll 1
    for (int s = 0; s <= TT + 1; ++s) {
        // ================= P1 =================
        if (g == 0) {
            if (s <= TT - 1) {
                dxv = xs[b * XSTR + s];
                if (s >= 1) {
                    const unsigned short* f0 = &hB0[(s + 1) & 1][b * HRUS];
                    const bf16x8 u0 = *(const bf16x8*)(f0 + 8 * q);
                    const bf16x8 u1 = *(const bf16x8*)(f0 + 32 + 8 * q);
                    const bf16x8 v0 = *(const bf16x8*)(f0 + 64 + 8 * q);
                    const bf16x8 v1 = *(const bf16x8*)(f0 + 96 + 8 * q);
                    f32x4 a0={0,0,0,0}, a1={0,0,0,0}, a2={0,0,0,0};
                    __builtin_amdgcn_s_setprio(1);
                    TILE6(a0, 0, u0, u1, v0, v1)
                    TILE6(a1, 1, u0, u1, v0, v1)
                    TILE6(a2, 2, u0, u1, v0, v1)
                    __builtin_amdgcn_s_setprio(0);
                    dA0 = a0; dA1 = a1; dA2 = a2;
                }
            }
        } else if (g == 1) {
            if (s >= 1 && s <= TT) {
                const unsigned short* f0 = &hB0[(s + 1) & 1][b * HRUS];
                const bf16x8 u0 = *(const bf16x8*)(f0 + 8 * q);
                const bf16x8 u1 = *(const bf16x8*)(f0 + 32 + 8 * q);
                const bf16x8 v0 = *(const bf16x8*)(f0 + 64 + 8 * q);
                const bf16x8 v1 = *(const bf16x8*)(f0 + 96 + 8 * q);
                f32x4 t0={0,0,0,0}, t1={0,0,0,0}, t2={0,0,0,0};
                __builtin_amdgcn_s_setprio(1);
                TILE6(t0, 0, u0, u1, v0, v1)
                TILE6(t1, 1, u0, u1, v0, v1)
                TILE6(t2, 2, u0, u1, v0, v1)
                __builtin_amdgcn_s_setprio(0);
                if (r < 8) {
                    float* p = gxp + (s & 1) * 1536;
                    *(f32x4*)(p)       = t0;
                    *(f32x4*)(p + 128) = t1;
                    *(f32x4*)(p + 256) = t2;
                }
            }
        } else {   // B2: gate h1(s-2)
            if (s >= 2) {
                const float* p = gxp + ((s & 1) ^ 1) * 1536;
                const f32x4 gx0 = *(const f32x4*)(p);
                const f32x4 gx1 = *(const f32x4*)(p + 128);
                const f32x4 gx2 = *(const f32x4*)(p + 256);
                #pragma unroll
                for (int k = 0; k < 4; ++k) {
                    float rr = fast_sigmoid(gx0[k] + gcr[k] + dB0[k]);
                    float zz = fast_sigmoid(gx1[k] + gcz[k] + dB1[k]);
                    float nn = fast_tanh(gx2[k] + gbn[k] + rr * (dB2[k] + ghn[k]));
                    hst[k] = fmaf(zz, hst[k] - nn, nn);
                }
                if (r < 8) PACK_WRITE(hB1 + b * HRUS + jb)
            }
        }
        __syncthreads();

        // ================= P2 =================
        if (g == 0) {
            if (s <= TT - 1) {
                #pragma unroll
                for (int k = 0; k < 4; ++k) {
                    float rr = fast_sigmoid(fmaf(dxv, gwr[k], gcr[k]) + dA0[k]);
                    float zz = fast_sigmoid(fmaf(dxv, gwz[k], gcz[k]) + dA1[k]);
                    float nn = fast_tanh(fmaf(dxv, gwn[k], gbn[k]) + rr * (dA2[k] + ghn[k]));
                    hst[k] = fmaf(zz, hst[k] - nn, nn);
                }
                if (r < 8) PACK_WRITE(hB0[s & 1] + b * HRUS + jb)
            }
        } else if (g == 2) {
            if (s >= 2 && s <= TT) {
                const unsigned short* f1 = hB1 + b * HRUS;
                const bf16x8 u0 = *(const bf16x8*)(f1 + 8 * q);
                const bf16x8 u1 = *(const bf16x8*)(f1 + 32 + 8 * q);
                const bf16x8 v0 = *(const bf16x8*)(f1 + 64 + 8 * q);
                const bf16x8 v1 = *(const bf16x8*)(f1 + 96 + 8 * q);
                f32x4 t0={0,0,0,0}, t1={0,0,0,0}, t2={0,0,0,0};
                __builtin_amdgcn_s_setprio(1);
                TILE6(t0, 0, u0, u1, v0, v1)
                TILE6(t1, 1, u0, u1, v0, v1)
                TILE6(t2, 2, u0, u1, v0, v1)
                __builtin_amdgcn_s_setprio(0);
                dB0 = t0; dB1 = t1; dB2 = t2;
            }
        }
        __syncthreads();
    }

    // ---- FC: h1(TT-1) is in hB1 rows 0-7 ----
    if (wave < 8) {
        const unsigned short* hrow = hB1 + wave * HRUS;
        float hi = __uint_as_float((unsigned)hrow[lane]      << 16);
        float lo = __uint_as_float((unsigned)hrow[64 + lane] << 16);
        float v = (hi + lo) * wfc;
        #pragma unroll
        for (int s = 32; s > 0; s >>= 1) v += __shfl_xor(v, s, 64);
        if (lane == 0) out[b0g + wave] = v + b_fc[0];
    }
}

extern "C" void kernel_launch(void* const* d_in, const int* in_sizes, int n_in,
                              void* d_out, int out_size, void* d_ws, size_t ws_size,
                              hipStream_t stream) {
    (void)in_sizes; (void)n_in; (void)out_size; (void)d_ws; (void)ws_size;
    gru_anti9<<<NWG, NW, 0, stream>>>(
        (const float*)d_in[0],
        (const float*)d_in[1], (const float*)d_in[2],
        (const float*)d_in[3], (const float*)d_in[4],
        (const float*)d_in[5], (const float*)d_in[6],
        (const float*)d_in[7], (const float*)d_in[8],
        (const float*)d_in[9], (const float*)d_in[10],
        (float*)d_out);
}